// Round 14
// baseline (470.955 us; speedup 1.0000x reference)
//
#include <hip/hip_runtime.h>

// Fused attention block: B=1, T=2048, D=2048, NH=16, NKV=4, HD=128, REP=4
//  prep:    xb = bf16(x); xmb = bf16((1-g)x + g*skip); colbias
//  convw:   weights fp32 -> bf16
//  gemm_sk: qrawp[2]  = xb  @ wq^T   (split-K=2, bf16 partials)
//  gemm_sk: kvrawp[4] = xmb @ [wk;wv]^T (+colbias on z==0) (split-K=4)
//  postqk:  sum partials + rmsnorm + rope -> qb (pre-scaled), kb
//  transv:  sum partials -> vT[h*128+d][t]
//  flash:   barrier-free causal GQA flash attn, 1 wave/block, direct L2
//           K/V fragment loads, LDS only for P transpose -> ao
//  gemm_sk: outp[2] = ao @ wproj^T (split-K=2)
//  reduce:  out = (outp0+outp1) * ln_s   (fp32)

typedef float  f32x4 __attribute__((ext_vector_type(4)));
typedef short  s16x8 __attribute__((ext_vector_type(8)));
typedef unsigned short u16;

#define DEVI __device__ __forceinline__

DEVI u16 f2bf(float f) {
  union { float f; unsigned u; } c; c.f = f;
  unsigned u = c.u + 0x7fffu + ((c.u >> 16) & 1u);
  return (u16)(u >> 16);
}
DEVI float bf2f(u16 v) {
  union { unsigned u; float f; } c; c.u = ((unsigned)v) << 16;
  return c.f;
}

DEVI void gl_lds16(const void* g, void* l) {
  __builtin_amdgcn_global_load_lds(
      (const __attribute__((address_space(1))) unsigned int*)g,
      (__attribute__((address_space(3))) unsigned int*)l, 16, 0, 0);
}

// ---------------- prep: x/xm conversion + colbias --------------------------
__global__ __launch_bounds__(256) void prep_kernel(
    const float* __restrict__ x, const float* __restrict__ skip,
    const float* __restrict__ ln_s, const float* __restrict__ v_bias,
    u16* __restrict__ xb, u16* __restrict__ xmb, float* __restrict__ colbias) {
  float g = 1.0f / (1.0f + __expf(-ln_s[0] * 0.1f));
  int i = (blockIdx.x * 256 + threadIdx.x) * 4;
  float4 xv = *(const float4*)(x + i);
  float4 sv = *(const float4*)(skip + i);
  ushort4 a, b;
  a.x = f2bf(xv.x); a.y = f2bf(xv.y); a.z = f2bf(xv.z); a.w = f2bf(xv.w);
  b.x = f2bf((1.f - g) * xv.x + g * sv.x);
  b.y = f2bf((1.f - g) * xv.y + g * sv.y);
  b.z = f2bf((1.f - g) * xv.z + g * sv.z);
  b.w = f2bf((1.f - g) * xv.w + g * sv.w);
  *(ushort4*)(xb + i) = a;
  *(ushort4*)(xmb + i) = b;
  if (blockIdx.x == 0) {
    int t = threadIdx.x;
    for (int k = t; k < 512; k += 256) {
      colbias[k] = 0.f;
      colbias[512 + k] = (1.f - g) * v_bias[k];
    }
  }
}

// ---------------- weight conversion fp32->bf16 -----------------------------
__global__ __launch_bounds__(256) void convw_kernel(
    const float* __restrict__ wq, const float* __restrict__ wk,
    const float* __restrict__ wv, const float* __restrict__ wp,
    u16* __restrict__ wb) {
  size_t i = ((size_t)blockIdx.x * 256 + threadIdx.x) * 4;
  constexpr size_t M4 = 4u * 1024 * 1024, M1 = 1024 * 1024;
  const float* src;
  if (i < M4) src = wq + i;
  else if (i < M4 + M1) src = wk + (i - M4);
  else if (i < M4 + 2 * M1) src = wv + (i - M4 - M1);
  else src = wp + (i - M4 - 2 * M1);
  float4 v = *(const float4*)src;
  ushort4 o;
  o.x = f2bf(v.x); o.y = f2bf(v.y); o.z = f2bf(v.z); o.w = f2bf(v.w);
  *(ushort4*)(wb + i) = o;
}

// ---------------- split-K NT GEMM: Cp[z] = A(:, zKS..) * B(:, zKS..)^T -----
// bf16 in, bf16 partial out. 128x128 tile, BK=32, 4 waves, gl_lds w=16.
template <int BIAS>
__global__ __launch_bounds__(256) void gemm_sk(
    const u16* __restrict__ A, const u16* __restrict__ B, u16* __restrict__ Cp,
    int M, int N, int KS, int K, const float* __restrict__ bias) {
  __shared__ u16 lA[128 * 32];
  __shared__ u16 lB[128 * 32];
  const int tid = threadIdx.x;
  const int lane = tid & 63, w = tid >> 6;
  const int m0 = blockIdx.y * 128, n0 = blockIdx.x * 128;
  const int z = blockIdx.z;
  const int mo = (w >> 1) * 64, no = (w & 1) * 64;
  const int r16 = lane & 15, q4 = lane >> 4;
  const int kbeg = z * KS;
  f32x4 acc[4][4] = {};

  for (int k0 = kbeg; k0 < kbeg + KS; k0 += 32) {
#pragma unroll
    for (int j = 0; j < 2; ++j) {
      int slot = j * 256 + tid;
      int row = slot >> 2, c8 = (slot & 3) * 8;
      gl_lds16(A + (size_t)(m0 + row) * K + k0 + c8, &lA[slot * 8]);
    }
#pragma unroll
    for (int j = 0; j < 2; ++j) {
      int slot = j * 256 + tid;
      int row = slot >> 2, c8 = (slot & 3) * 8;
      gl_lds16(B + (size_t)(n0 + row) * K + k0 + c8, &lB[slot * 8]);
    }
    __syncthreads();
    s16x8 af[4], bfr[4];
#pragma unroll
    for (int i = 0; i < 4; ++i)
      af[i] = *(const s16x8*)&lA[(mo + i * 16 + r16) * 32 + q4 * 8];
#pragma unroll
    for (int i = 0; i < 4; ++i)
      bfr[i] = *(const s16x8*)&lB[(no + i * 16 + r16) * 32 + q4 * 8];
#pragma unroll
    for (int mi = 0; mi < 4; ++mi)
#pragma unroll
      for (int ni = 0; ni < 4; ++ni)
        acc[mi][ni] = __builtin_amdgcn_mfma_f32_16x16x32_bf16(
            af[mi], bfr[ni], acc[mi][ni], 0, 0, 0);
    __syncthreads();
  }
  u16* Cz = Cp + (size_t)z * M * N;
#pragma unroll
  for (int mi = 0; mi < 4; ++mi) {
#pragma unroll
    for (int ni = 0; ni < 4; ++ni) {
      int col = n0 + no + ni * 16 + r16;
      float bv = (BIAS && z == 0) ? bias[col] : 0.0f;
#pragma unroll
      for (int r = 0; r < 4; ++r) {
        int row = m0 + mo + mi * 16 + q4 * 4 + r;
        Cz[(size_t)row * N + col] = f2bf(acc[mi][ni][r] + bv);
      }
    }
  }
}

// ---------------- rmsnorm + rope (sums split-K partials) -------------------
// q pre-scaled by gain^2 * (1/sqrt(128)) * log2(e) so flash softmax is exp2.
__global__ __launch_bounds__(256) void postqk_kernel(
    const u16* __restrict__ qrawp, const u16* __restrict__ kvrawp,
    const float* __restrict__ qk_g, u16* __restrict__ qb,
    u16* __restrict__ kb) {
  constexpr int T = 2048;
  constexpr size_t QPS = (size_t)T * 2048;  // q partial stride (elems)
  constexpr size_t KPS = (size_t)T * 1024;  // kv partial stride
  const int lane = threadIdx.x & 63, w = threadIdx.x >> 6;
  int p = blockIdx.x * 4 + w;  // 0..20*T-1
  u16* dst;
  int t;
  float x1, x2, extra = 1.0f;
  if (p < 16 * T) {
    int hh = p >> 11; t = p & 2047;
    const u16* s0 = qrawp + (size_t)t * 2048 + hh * 128;
    x1 = bf2f(s0[lane]) + bf2f(s0[QPS + lane]);
    x2 = bf2f(s0[lane + 64]) + bf2f(s0[QPS + lane + 64]);
    dst = qb + ((size_t)hh * T + t) * 128;
    float g = qk_g[hh];
    extra = g * g * 0.12751742f;  // 0.08838834765 * log2(e)
  } else {
    p -= 16 * T;
    int hh = p >> 11; t = p & 2047;
    const u16* s0 = kvrawp + (size_t)t * 1024 + hh * 128;
    x1 = bf2f(s0[lane]) + bf2f(s0[KPS + lane]) + bf2f(s0[2 * KPS + lane]) +
         bf2f(s0[3 * KPS + lane]);
    x2 = bf2f(s0[lane + 64]) + bf2f(s0[KPS + lane + 64]) +
         bf2f(s0[2 * KPS + lane + 64]) + bf2f(s0[3 * KPS + lane + 64]);
    dst = kb + ((size_t)hh * T + t) * 128;
  }
  float ss = x1 * x1 + x2 * x2;
  ss += __shfl_xor(ss, 1);  ss += __shfl_xor(ss, 2);  ss += __shfl_xor(ss, 4);
  ss += __shfl_xor(ss, 8);  ss += __shfl_xor(ss, 16); ss += __shfl_xor(ss, 32);
  float rn = rsqrtf(ss * (1.0f / 128.0f) + 1.1920929e-7f) * extra;
  float fr = (float)t * expf((float)lane * -0.14391156831212787f);
  float c = cosf(fr), s = sinf(fr);
  float y1 = (x1 * c + x2 * s) * rn;
  float y2 = (x2 * c - x1 * s) * rn;
  dst[lane] = f2bf(y1);
  dst[lane + 64] = f2bf(y2);
}

// ---------------- transpose v (sums 4 partials): vT[hd][t] -----------------
__global__ __launch_bounds__(256) void transv_kernel(
    const u16* __restrict__ kvrawp, u16* __restrict__ vT) {
  constexpr int T = 2048;
  constexpr size_t KPS = (size_t)T * 1024;
  __shared__ float tile[32][33];
  int t0 = blockIdx.x * 32, hd0 = blockIdx.y * 32;
  int tx = threadIdx.x & 31, ty = threadIdx.x >> 5;  // ty 0..7
#pragma unroll
  for (int i = 0; i < 4; ++i) {
    int t = t0 + ty + i * 8;
    const u16* s0 = kvrawp + (size_t)t * 1024 + 512 + hd0 + tx;
    tile[ty + i * 8][tx] =
        bf2f(s0[0]) + bf2f(s0[KPS]) + bf2f(s0[2 * KPS]) + bf2f(s0[3 * KPS]);
  }
  __syncthreads();
#pragma unroll
  for (int i = 0; i < 4; ++i) {
    int hd = hd0 + ty + i * 8;
    vT[(size_t)hd * T + t0 + tx] = f2bf(tile[tx][ty + i * 8]);
  }
}

// ---------------- causal GQA flash attention (v3: barrier-free) ------------
// grid (128 qtiles reversed, 16 heads), 64 threads = 1 wave, 16 q-rows/wave.
// K/V fragments loaded directly from global (L2-resident); LDS only for P.
__global__ __launch_bounds__(64) void flash_kernel(
    const u16* __restrict__ qb, const u16* __restrict__ kb,
    const u16* __restrict__ vT, u16* __restrict__ out) {
  constexpr int T = 2048;
  __shared__ u16 lP[16 * 72];  // wave-local P transpose buffer
  const int lane = threadIdx.x;
  const int h = blockIdx.y, hkv = h >> 2;
  const int qt = (int)(gridDim.x - 1 - blockIdx.x);
  const int q0w = qt * 16;
  const int r16 = lane & 15, q4 = lane >> 4;
  const int qrow = q0w + q4 * 4;  // + r

  s16x8 qf[4];
  {
    const u16* qp = qb + ((size_t)h * T + q0w + r16) * 128 + q4 * 8;
#pragma unroll
    for (int d = 0; d < 4; ++d) qf[d] = *(const s16x8*)(qp + d * 32);
  }
  const u16* kbase = kb + (size_t)hkv * T * 128;
  const u16* vbase = vT + (size_t)hkv * 128 * T;

  f32x4 O[8] = {};
  float m_[4], l_[4];
#pragma unroll
  for (int r = 0; r < 4; ++r) { m_[r] = -3.0e38f; l_[r] = 0.f; }
  const int nt = q0w / 64 + 1;

  for (int it = 0; it < nt; ++it) {
    const int t0 = it * 64;
    // ---- QK^T: B-fragments of K straight from global ----
    f32x4 s[4];
    const u16* kt = kbase + (size_t)t0 * 128 + q4 * 8;
#pragma unroll
    for (int kvh = 0; kvh < 4; ++kvh) {
      const u16* kr = kt + (kvh * 16 + r16) * 128;
      f32x4 acc = {};
      acc = __builtin_amdgcn_mfma_f32_16x16x32_bf16(qf[0], *(const s16x8*)(kr), acc, 0, 0, 0);
      acc = __builtin_amdgcn_mfma_f32_16x16x32_bf16(qf[1], *(const s16x8*)(kr + 32), acc, 0, 0, 0);
      acc = __builtin_amdgcn_mfma_f32_16x16x32_bf16(qf[2], *(const s16x8*)(kr + 64), acc, 0, 0, 0);
      acc = __builtin_amdgcn_mfma_f32_16x16x32_bf16(qf[3], *(const s16x8*)(kr + 96), acc, 0, 0, 0);
      s[kvh] = acc;
    }
    // ---- prefetch V half0 (kv 0..31) while softmax runs ----
    const u16* vt = vbase + t0 + q4 * 8;
    s16x8 vf[8];
#pragma unroll
    for (int dt = 0; dt < 8; ++dt)
      vf[dt] = *(const s16x8*)(vt + (size_t)(dt * 16 + r16) * T);

    // ---- causal mask (only the diagonal tile) ----
    if (t0 + 64 > q0w) {
#pragma unroll
      for (int kvh = 0; kvh < 4; ++kvh)
#pragma unroll
        for (int r = 0; r < 4; ++r)
          s[kvh][r] = (t0 + kvh * 16 + r16 <= qrow + r) ? s[kvh][r] : -1.0e30f;
    }
    // ---- online softmax (exp2-space; scale folded into Q) ----
    float al[4];
#pragma unroll
    for (int r = 0; r < 4; ++r) {
      float t = fmaxf(fmaxf(s[0][r], s[1][r]), fmaxf(s[2][r], s[3][r]));
      t = fmaxf(t, __shfl_xor(t, 1));
      t = fmaxf(t, __shfl_xor(t, 2));
      t = fmaxf(t, __shfl_xor(t, 4));
      t = fmaxf(t, __shfl_xor(t, 8));
      float mn = fmaxf(m_[r], t);
      al[r] = __builtin_amdgcn_exp2f(m_[r] - mn);
      m_[r] = mn;
    }
#pragma unroll
    for (int r = 0; r < 4; ++r) {
      float ps = 0.f;
      int prow = (q4 * 4 + r) * 72;
#pragma unroll
      for (int kvh = 0; kvh < 4; ++kvh) {
        float pp = __builtin_amdgcn_exp2f(s[kvh][r] - m_[r]);
        lP[prow + kvh * 16 + r16] = f2bf(pp);
        ps += pp;
      }
      ps += __shfl_xor(ps, 1); ps += __shfl_xor(ps, 2);
      ps += __shfl_xor(ps, 4); ps += __shfl_xor(ps, 8);
      l_[r] = l_[r] * al[r] + ps;
    }
#pragma unroll
    for (int dt = 0; dt < 8; ++dt)
#pragma unroll
      for (int r = 0; r < 4; ++r) O[dt][r] *= al[r];

    asm volatile("s_waitcnt lgkmcnt(0)" ::: "memory");
    __builtin_amdgcn_sched_barrier(0);
    s16x8 pf0 = *(const s16x8*)&lP[r16 * 72 + q4 * 8];
    s16x8 pf1 = *(const s16x8*)&lP[r16 * 72 + 32 + q4 * 8];

    // ---- PV half0 ----
#pragma unroll
    for (int dt = 0; dt < 8; ++dt)
      O[dt] = __builtin_amdgcn_mfma_f32_16x16x32_bf16(pf0, vf[dt], O[dt], 0, 0, 0);
    // ---- V half1 + PV half1 ----
#pragma unroll
    for (int dt = 0; dt < 8; ++dt)
      vf[dt] = *(const s16x8*)(vt + 32 + (size_t)(dt * 16 + r16) * T);
#pragma unroll
    for (int dt = 0; dt < 8; ++dt)
      O[dt] = __builtin_amdgcn_mfma_f32_16x16x32_bf16(pf1, vf[dt], O[dt], 0, 0, 0);
  }

  float inv[4];
#pragma unroll
  for (int r = 0; r < 4; ++r) inv[r] = 1.0f / l_[r];
#pragma unroll
  for (int dt = 0; dt < 8; ++dt) {
#pragma unroll
    for (int r = 0; r < 4; ++r) {
      int row = qrow + r;
      int col = h * 128 + dt * 16 + r16;
      out[(size_t)row * 2048 + col] = f2bf(O[dt][r] * inv[r]);
    }
  }
}

// ---------------- final reduce: out = (p0+p1) * ln_s -----------------------
__global__ __launch_bounds__(256) void reduce_out_kernel(
    const u16* __restrict__ p, const float* __restrict__ ln_s,
    float* __restrict__ out) {
  constexpr size_t PS = (size_t)2048 * 2048;
  float sc = ln_s[0];
  size_t i = ((size_t)blockIdx.x * 256 + threadIdx.x) * 4;
  ushort4 a = *(const ushort4*)(p + i);
  ushort4 b = *(const ushort4*)(p + PS + i);
  float4 o;
  o.x = (bf2f(a.x) + bf2f(b.x)) * sc;
  o.y = (bf2f(a.y) + bf2f(b.y)) * sc;
  o.z = (bf2f(a.z) + bf2f(b.z)) * sc;
  o.w = (bf2f(a.w) + bf2f(b.w)) * sc;
  *(float4*)(out + i) = o;
}

// ---------------------------------------------------------------------------
extern "C" void kernel_launch(void* const* d_in, const int* in_sizes, int n_in,
                              void* d_out, int out_size, void* d_ws,
                              size_t ws_size, hipStream_t stream) {
  const float* x      = (const float*)d_in[0];
  const float* skip   = (const float*)d_in[1];
  const float* wq     = (const float*)d_in[2];
  const float* wk     = (const float*)d_in[3];
  const float* wv     = (const float*)d_in[4];
  const float* wp     = (const float*)d_in[5];
  const float* qk_g   = (const float*)d_in[6];
  const float* ln_s   = (const float*)d_in[7];
  const float* v_bias = (const float*)d_in[8];
  float* out = (float*)d_out;

  constexpr size_t MB = 1024 * 1024;
  char* ws = (char*)d_ws;
  u16*   wb     = (u16*)(ws);             // 20MB: wq|wk|wv|wp (bf16)
  u16*   xb     = (u16*)(ws + 20 * MB);   // 8MB  (ao overlays later)
  u16*   xmb    = (u16*)(ws + 28 * MB);   // 8MB
  u16*   qrawp  = (u16*)(ws + 36 * MB);   // 16MB: 2 partials (outp overlays)
  u16*   kvrawp = (u16*)(ws + 52 * MB);   // 16MB: 4 partials
  u16*   qb     = (u16*)(ws + 68 * MB);   // 8MB
  u16*   kb     = (u16*)(ws + 76 * MB);   // 2MB
  u16*   vT     = (u16*)(ws + 78 * MB);   // 2MB
  float* colbias = (float*)(ws + 80 * MB);
  u16*   ao     = xb;      // xb dead after gemm q
  u16*   outp   = qrawp;   // qrawp dead after postqk

  prep_kernel<<<4096, 256, 0, stream>>>(x, skip, ln_s, v_bias, xb, xmb,
                                        colbias);
  convw_kernel<<<10240, 256, 0, stream>>>(wq, wk, wv, wp, wb);
  gemm_sk<0><<<dim3(16, 16, 2), 256, 0, stream>>>(
      xb, wb, qrawp, 2048, 2048, 1024, 2048, nullptr);
  gemm_sk<1><<<dim3(8, 16, 4), 256, 0, stream>>>(
      xmb, wb + 4 * MB, kvrawp, 2048, 1024, 512, 2048, colbias);
  postqk_kernel<<<10240, 256, 0, stream>>>(qrawp, kvrawp, qk_g, qb, kb);
  transv_kernel<<<dim3(64, 16), 256, 0, stream>>>(kvrawp, vT);
  flash_kernel<<<dim3(128, 16), 64, 0, stream>>>(qb, kb, vT, ao);
  gemm_sk<0><<<dim3(16, 16, 2), 256, 0, stream>>>(
      ao, wb + 6 * MB, outp, 2048, 2048, 1024, 2048, nullptr);
  reduce_out_kernel<<<4096, 256, 0, stream>>>(outp, ln_s, out);
}